// Round 2
// 986.465 us; speedup vs baseline: 1.1628x; 1.1628x over previous
//
#include <hip/hip_runtime.h>
#include <hip/hip_bf16.h>
#include <stdint.h>

// Problem constants (fixed by the reference).
constexpr int B_ = 8;
constexpr int S_ = 2048;
constexpr int K_ = 4096;
constexpr int M_ = 4096;

typedef __bf16 bf16x8 __attribute__((ext_vector_type(8)));
typedef float  f32x4  __attribute__((ext_vector_type(4)));
typedef unsigned short ushort8v __attribute__((ext_vector_type(8)));

// 16B async global->LDS copy. LDS dest must be wave-uniform-base + lane*16.
__device__ __forceinline__ void async16(const void* g, void* l) {
  __builtin_amdgcn_global_load_lds(
      (__attribute__((address_space(1))) unsigned int*)(g),
      (__attribute__((address_space(3))) unsigned int*)(l),
      16, 0, 0);
}

// ---------------------------------------------------------------------------
// Mask format detection (unchanged; known working).
// ---------------------------------------------------------------------------
__global__ void detect_mask_kernel(const uint32_t* __restrict__ mw, int nwords,
                                   int* __restrict__ flag_out) {
  __shared__ int s_float, s_hi;
  if (threadIdx.x == 0) { s_float = 0; s_hi = 0; }
  __syncthreads();
  int f_float = 0, f_hi = 0;
  for (int i = threadIdx.x; i < nwords; i += blockDim.x) {
    uint32_t w = mw[i];
    if (w == 0x3F800000u) f_float = 1;
    else if (w & 0xFFFFFF00u) f_hi = 1;
  }
  if (f_float) atomicOr(&s_float, 1);
  if (f_hi)    atomicOr(&s_hi, 1);
  __syncthreads();
  if (threadIdx.x == 0) flag_out[0] = s_float ? 2 : (s_hi ? 1 : 0);
}

__device__ __forceinline__ bool mask_bit(const void* mask, int flag, size_t idx) {
  if (flag == 1) return ((const uint8_t*)mask)[idx] != 0;
  if (flag == 2) return ((const float*)mask)[idx] != 0.0f;
  return ((const int*)mask)[idx] != 0;
}

// Wb[m,k] = bf16( W[m,k] * mask[m,k] )
__global__ void build_wb_kernel(const float* __restrict__ w, const void* __restrict__ mask,
                                const int* __restrict__ flagp,
                                __hip_bfloat16* __restrict__ wb, int n) {
  const int flag = flagp[0];
  int idx = (blockIdx.x * blockDim.x + threadIdx.x) * 4;
  if (idx >= n) return;
  float4 v = *(const float4*)(w + idx);
  float m0, m1, m2, m3;
  if (flag == 1) {
    uchar4 mv = *(const uchar4*)((const uint8_t*)mask + idx);
    m0 = mv.x ? 1.f : 0.f; m1 = mv.y ? 1.f : 0.f;
    m2 = mv.z ? 1.f : 0.f; m3 = mv.w ? 1.f : 0.f;
  } else if (flag == 2) {
    float4 mv = *(const float4*)((const float*)mask + idx);
    m0 = mv.x != 0.f ? 1.f : 0.f; m1 = mv.y != 0.f ? 1.f : 0.f;
    m2 = mv.z != 0.f ? 1.f : 0.f; m3 = mv.w != 0.f ? 1.f : 0.f;
  } else {
    int4 mv = *(const int4*)((const int*)mask + idx);
    m0 = mv.x ? 1.f : 0.f; m1 = mv.y ? 1.f : 0.f;
    m2 = mv.z ? 1.f : 0.f; m3 = mv.w ? 1.f : 0.f;
  }
  union { ushort4 u4; __hip_bfloat16 h[4]; } o;
  o.h[0] = __float2bfloat16(v.x * m0);
  o.h[1] = __float2bfloat16(v.y * m1);
  o.h[2] = __float2bfloat16(v.z * m2);
  o.h[3] = __float2bfloat16(v.w * m3);
  *(ushort4*)(wb + idx) = o.u4;
}

// Xb = bf16(x): 8 floats/thread, 16B store.
__global__ void cvt_x_kernel(const float* __restrict__ x,
                             __hip_bfloat16* __restrict__ xb, int n) {
  int idx = (blockIdx.x * blockDim.x + threadIdx.x) * 8;
  if (idx >= n) return;
  float4 v0 = *(const float4*)(x + idx);
  float4 v1 = *(const float4*)(x + idx + 4);
  union { ushort8v u; __hip_bfloat16 h[8]; } o;
  o.h[0] = __float2bfloat16(v0.x); o.h[1] = __float2bfloat16(v0.y);
  o.h[2] = __float2bfloat16(v0.z); o.h[3] = __float2bfloat16(v0.w);
  o.h[4] = __float2bfloat16(v1.x); o.h[5] = __float2bfloat16(v1.y);
  o.h[6] = __float2bfloat16(v1.z); o.h[7] = __float2bfloat16(v1.w);
  *(ushort8v*)(xb + idx) = o.u;
}

// ---------------------------------------------------------------------------
// 256x256-tile, BK=64, 8-wave, 4-phase/K-tile pipelined bf16 GEMM (m201-style).
//   C[b][m][s] = sum_k Wb[m][k] * Xb[b][s][k]
//
// LDS: lds[buf][op(A/B)][kplane(k0/k32)][256*32] bf16 = 128 KiB.
//   Each plane row is 32 bf16 = 64B = 4x16B chunks. Swizzle: the 16B chunk
//   index is XORed with ((row>>1)&3). Applied on BOTH the staging global
//   source address (LDS dest stays gload_lds-linear) and the ds_read address.
//   => frag ds_read_b128: 16-lane group spreads 2 lanes per bank-quad
//      (uniform over all 32 banks) -> conflict-free.
//
// Schedule per K-tile t (computing from buf CUR, staging tile t+1 into NXT):
//   ph0: read A(k0) frags i0-3 + B(k0) frags j0-3 | stage A_k0(t+1) | bar |
//        lgkmcnt(0) | prio1 16xMFMA prio0 | bar
//   ph1: read A(k0) i4-7                  | stage B_k0(t+1) | bar |
//        lgkmcnt(0) | prio1 16xMFMA prio0 | vmcnt(4) | bar
//   ph2/ph3: same on k32 planes; ph3 ends with vmcnt(4) | bar.
// vmcnt(4) proof: at ph1's wait, the only loads allowed outstanding are the
//   4 issued this tile (ph0+ph1) => A_k32(t),B_k32(t) (staged last tile)
//   have landed before ph2 reads them. Symmetric at ph3 for the next tile's
//   k0 planes. Loads never drain to 0 in steady state (T3+T4).
// ---------------------------------------------------------------------------
__global__ __launch_bounds__(512, 2) void gemm8p_kernel(
    const __hip_bfloat16* __restrict__ A,   // Wb [M,K]
    const __hip_bfloat16* __restrict__ X,   // Xb [B,S,K]
    float* __restrict__ C) {                // [B,M,S]
  constexpr int BK = 64;
  // alignas(16): global_load_lds width=16 requires 16B-aligned LDS dest.
  alignas(16) __shared__ __hip_bfloat16 lds[2][2][2][256 * 32];   // 128 KiB

  const int tid  = threadIdx.x;
  const int lane = tid & 63;
  const int wv   = tid >> 6;       // 0..7
  const int wm   = wv >> 2;        // 0..1  -> 128-row A panel
  const int wn   = wv & 3;         // 0..3  -> 64-row B panel
  const int lr   = lane & 15;
  const int lq   = lane >> 4;

  // Bijective XCD swizzle: 1024 blocks, 128 per XCD = one batch per XCD,
  // m-fastest within a batch (keeps the 2 live X panels L2-resident).
  const int bid = blockIdx.x;
  const int swz = (bid & 7) * 128 + (bid >> 3);
  const int b   = swz >> 7;
  const int t_  = swz & 127;
  const int mz  = t_ & 15;
  const int sz  = t_ >> 4;

  const size_t bm = (size_t)mz * 256;
  const size_t bs = (size_t)sz * 256;

  const __hip_bfloat16* Ag = A + bm * K_;
  const __hip_bfloat16* Xg = X + (size_t)b * S_ * K_ + bs * K_;
  float* Cg = C + (size_t)b * M_ * S_ + bm * S_ + bs;

  // Staging constants: thread's 2 loads per plane cover linear LDS chunks
  // {tid, tid+512}; row = chunk>>2, lds-chunk = chunk&3,
  // global-chunk = ldschunk ^ ((row>>1)&3) = (tid&3) ^ ((tid>>3)&3).
  // (row+128 keeps the same xor term: 64 = 0 mod 4.)
  const int    srow = tid >> 2;                                  // + 128 for q=1
  const int    scg  = ((tid & 3) ^ ((tid >> 3) & 3)) * 8;        // bf16 units
  const int    sldso = tid * 8;                                  // + 4096 for q=1
  const __hip_bfloat16* Ags = Ag + (size_t)srow * K_ + scg;
  const __hip_bfloat16* Xgs = Xg + (size_t)srow * K_ + scg;

  // Frag-read offsets (elements within a plane). Frag row = rbase + i*16;
  // since the row-dependent swizzle term is invariant mod 4 under +i*16, the
  // swizzled chunk is a per-thread constant -> reads are base + i*512.
  const int rA   = wm * 128 + lr;
  const int offA = rA * 32 + (lq ^ ((rA >> 1) & 3)) * 8;
  const int rB   = wn * 64 + lr;
  const int offB = rB * 32 + (lq ^ ((rB >> 1) & 3)) * 8;

  f32x4 acc[8][4];
#pragma unroll
  for (int i = 0; i < 8; i++)
#pragma unroll
    for (int j = 0; j < 4; j++) acc[i][j] = f32x4{0.f, 0.f, 0.f, 0.f};

#define LDF(p, off) (*(const bf16x8*)(const void*)((p) + (off)))

#define STAGE_PLANE(gbase, ldsplane) do {                                   \
    async16((gbase),                    (ldsplane) + sldso);                \
    async16((gbase) + (size_t)128 * K_, (ldsplane) + sldso + 4096);         \
  } while (0)

#define CFENCE asm volatile("" ::: "memory")

// lgkmcnt(0) drain + sched_barrier(0): rule #18 — never let the scheduler
// hoist the MFMA cluster above the LDS-wait.
#define LGKM0 do {                                                          \
    asm volatile("s_waitcnt lgkmcnt(0)" ::: "memory");                      \
    __builtin_amdgcn_sched_barrier(0);                                      \
  } while (0)

#define MM4(I, AA) do {                                                        \
    acc[I][0] = __builtin_amdgcn_mfma_f32_16x16x32_bf16(AA, b0, acc[I][0], 0, 0, 0); \
    acc[I][1] = __builtin_amdgcn_mfma_f32_16x16x32_bf16(AA, b1, acc[I][1], 0, 0, 0); \
    acc[I][2] = __builtin_amdgcn_mfma_f32_16x16x32_bf16(AA, b2, acc[I][2], 0, 0, 0); \
    acc[I][3] = __builtin_amdgcn_mfma_f32_16x16x32_bf16(AA, b3, acc[I][3], 0, 0, 0); \
  } while (0)

#define TILE_BODY(CUR, NXT, KT, DOSTAGE) do {                               \
    const __hip_bfloat16* pA0 = &lds[CUR][0][0][0];                         \
    const __hip_bfloat16* pA1 = &lds[CUR][0][1][0];                         \
    const __hip_bfloat16* pB0 = &lds[CUR][1][0][0];                         \
    const __hip_bfloat16* pB1 = &lds[CUR][1][1][0];                         \
    bf16x8 a0, a1, a2, a3, a4, a5, a6, a7, b0, b1, b2, b3;                  \
    /* ---- phase 0: k0 plane, m-frags 0-3 ---- */                          \
    a0 = LDF(pA0, offA);        a1 = LDF(pA0, offA + 512);                  \
    a2 = LDF(pA0, offA + 1024); a3 = LDF(pA0, offA + 1536);                 \
    b0 = LDF(pB0, offB);        b1 = LDF(pB0, offB + 512);                  \
    b2 = LDF(pB0, offB + 1024); b3 = LDF(pB0, offB + 1536);                 \
    if (DOSTAGE) STAGE_PLANE(Ags + (KT) + BK, &lds[NXT][0][0][0]);          \
    __builtin_amdgcn_s_barrier(); CFENCE;                                   \
    LGKM0;                                                                  \
    __builtin_amdgcn_s_setprio(1);                                          \
    MM4(0, a0); MM4(1, a1); MM4(2, a2); MM4(3, a3);                         \
    __builtin_amdgcn_s_setprio(0);                                          \
    __builtin_amdgcn_s_barrier(); CFENCE;                                   \
    /* ---- phase 1: k0 plane, m-frags 4-7 ---- */                          \
    a4 = LDF(pA0, offA + 2048); a5 = LDF(pA0, offA + 2560);                 \
    a6 = LDF(pA0, offA + 3072); a7 = LDF(pA0, offA + 3584);                 \
    if (DOSTAGE) STAGE_PLANE(Xgs + (KT) + BK, &lds[NXT][1][0][0]);          \
    __builtin_amdgcn_s_barrier(); CFENCE;                                   \
    LGKM0;                                                                  \
    __builtin_amdgcn_s_setprio(1);                                          \
    MM4(4, a4); MM4(5, a5); MM4(6, a6); MM4(7, a7);                         \
    __builtin_amdgcn_s_setprio(0);                                          \
    if (DOSTAGE) { asm volatile("s_waitcnt vmcnt(4)" ::: "memory"); }       \
    else         { asm volatile("s_waitcnt vmcnt(0)" ::: "memory"); }       \
    __builtin_amdgcn_s_barrier(); CFENCE;                                   \
    /* ---- phase 2: k32 plane, m-frags 0-3 ---- */                         \
    a0 = LDF(pA1, offA);        a1 = LDF(pA1, offA + 512);                  \
    a2 = LDF(pA1, offA + 1024); a3 = LDF(pA1, offA + 1536);                 \
    b0 = LDF(pB1, offB);        b1 = LDF(pB1, offB + 512);                  \
    b2 = LDF(pB1, offB + 1024); b3 = LDF(pB1, offB + 1536);                 \
    if (DOSTAGE) STAGE_PLANE(Ags + (KT) + BK + 32, &lds[NXT][0][1][0]);     \
    __builtin_amdgcn_s_barrier(); CFENCE;                                   \
    LGKM0;                                                                  \
    __builtin_amdgcn_s_setprio(1);                                          \
    MM4(0, a0); MM4(1, a1); MM4(2, a2); MM4(3, a3);                         \
    __builtin_amdgcn_s_setprio(0);                                          \
    __builtin_amdgcn_s_barrier(); CFENCE;                                   \
    /* ---- phase 3: k32 plane, m-frags 4-7 ---- */                         \
    a4 = LDF(pA1, offA + 2048); a5 = LDF(pA1, offA + 2560);                 \
    a6 = LDF(pA1, offA + 3072); a7 = LDF(pA1, offA + 3584);                 \
    if (DOSTAGE) STAGE_PLANE(Xgs + (KT) + BK + 32, &lds[NXT][1][1][0]);     \
    __builtin_amdgcn_s_barrier(); CFENCE;                                   \
    LGKM0;                                                                  \
    __builtin_amdgcn_s_setprio(1);                                          \
    MM4(4, a4); MM4(5, a5); MM4(6, a6); MM4(7, a7);                         \
    __builtin_amdgcn_s_setprio(0);                                          \
    if (DOSTAGE) { asm volatile("s_waitcnt vmcnt(4)" ::: "memory"); }       \
    else         { asm volatile("s_waitcnt vmcnt(0)" ::: "memory"); }       \
    __builtin_amdgcn_s_barrier(); CFENCE;                                   \
  } while (0)

  // Prologue: stage tile 0 in publish order A_k0, B_k0, A_k32, B_k32.
  STAGE_PLANE(Ags,      &lds[0][0][0][0]);
  STAGE_PLANE(Xgs,      &lds[0][1][0][0]);
  STAGE_PLANE(Ags + 32, &lds[0][0][1][0]);
  STAGE_PLANE(Xgs + 32, &lds[0][1][1][0]);
  asm volatile("s_waitcnt vmcnt(4)" ::: "memory");  // k0 planes landed
  __builtin_amdgcn_s_barrier(); CFENCE;

  int kt = 0;
#pragma unroll 1
  for (; kt < K_ - 2 * BK; kt += 2 * BK) {
    TILE_BODY(0, 1, kt, true);
    TILE_BODY(1, 0, kt + BK, true);
  }
  TILE_BODY(0, 1, kt, true);        // tile 62, stages tile 63
  TILE_BODY(1, 0, kt + BK, false);  // tile 63, no staging, drains vmcnt

  // Epilogue: C[row][col], col=lane&15, row=(lane>>4)*4+r  [verified m89/m91]
#pragma unroll
  for (int i = 0; i < 8; i++) {
#pragma unroll
    for (int j = 0; j < 4; j++) {
      const int row = wm * 128 + i * 16 + lq * 4;
      const int col = wn * 64 + j * 16 + lr;
#pragma unroll
      for (int r = 0; r < 4; r++)
        Cg[(size_t)(row + r) * S_ + col] = acc[i][j][r];
    }
  }

#undef TILE_BODY
#undef MM4
#undef LGKM0
#undef CFENCE
#undef STAGE_PLANE
#undef LDF
}

// ---------------------------------------------------------------------------
// Fallback (only if ws_size too small for staging buffers): fp32 LDS-tiled.
// ---------------------------------------------------------------------------
__global__ void fb_gemm_kernel(const float* __restrict__ x, const float* __restrict__ w,
                               const void* __restrict__ mask, const int* __restrict__ flagp,
                               float* __restrict__ out) {
  __shared__ float sW[16][17];
  __shared__ float sX[16][17];
  const int flag = flagp[0];
  const int tx = threadIdx.x, ty = threadIdx.y;
  const int m0 = blockIdx.x * 16, s0 = blockIdx.y * 16, b = blockIdx.z;
  float acc = 0.f;
  for (int kt = 0; kt < K_; kt += 16) {
    const size_t wi = (size_t)(m0 + ty) * K_ + kt + tx;
    sW[ty][tx] = mask_bit(mask, flag, wi) ? w[wi] : 0.f;
    sX[ty][tx] = x[(size_t)b * S_ * K_ + (size_t)(s0 + ty) * K_ + kt + tx];
    __syncthreads();
#pragma unroll
    for (int kk = 0; kk < 16; kk++) acc += sW[ty][kk] * sX[tx][kk];
    __syncthreads();
  }
  out[(size_t)b * M_ * S_ + (size_t)(m0 + ty) * S_ + s0 + tx] = acc;
}

extern "C" void kernel_launch(void* const* d_in, const int* in_sizes, int n_in,
                              void* d_out, int out_size, void* d_ws, size_t ws_size,
                              hipStream_t stream) {
  const float* x    = (const float*)d_in[0];
  const float* w    = (const float*)d_in[1];
  const void*  mask = d_in[2];
  float* out = (float*)d_out;

  uint8_t* ws = (uint8_t*)d_ws;
  int* flag = (int*)ws;
  const size_t offW = 256;
  const size_t offX = offW + (size_t)M_ * K_ * sizeof(__hip_bfloat16);
  const size_t need = offX + (size_t)B_ * S_ * K_ * sizeof(__hip_bfloat16);

  detect_mask_kernel<<<1, 256, 0, stream>>>((const uint32_t*)mask, 16384, flag);

  if (ws_size >= need) {
    __hip_bfloat16* Wb = (__hip_bfloat16*)(ws + offW);
    __hip_bfloat16* Xb = (__hip_bfloat16*)(ws + offX);
    build_wb_kernel<<<(M_ * K_) / 1024, 256, 0, stream>>>(w, mask, flag, Wb, M_ * K_);
    cvt_x_kernel<<<(B_ * S_ * K_) / 2048, 256, 0, stream>>>(x, Xb, B_ * S_ * K_);
    static_assert(M_ % 256 == 0 && S_ % 256 == 0, "tile divisibility");
    gemm8p_kernel<<<dim3((M_ / 256) * (S_ / 256) * B_), dim3(512), 0, stream>>>(Wb, Xb, out);
  } else {
    dim3 grid(M_ / 16, S_ / 16, B_);
    fb_gemm_kernel<<<grid, dim3(16, 16), 0, stream>>>(x, w, mask, flag, out);
  }
}